// Round 11
// baseline (1909.535 us; speedup 1.0000x reference)
//
#include <hip/hip_runtime.h>
#include <hip/hip_bf16.h>

typedef unsigned short u16;
typedef __attribute__((ext_vector_type(8))) __bf16 bf16x8;
typedef __attribute__((ext_vector_type(4))) float f32x4;

#define TOK 16384
#define DM  1024
#define HD  4096
#define NE  8
#define NG  128
#define GSZ 128
#define CAPM 31               // usable slots per (group, expert)
#define MEP (NG*32)           // 4096 padded rows per expert (slot 31 = zero pad)

static __device__ __forceinline__ u16 f2b(float f) {
  union { float f; unsigned u; } v; v.f = f;
  unsigned r = v.u + 0x7fffu + ((v.u >> 16) & 1u);
  return (u16)(r >> 16);
}
static __device__ __forceinline__ float b2f(u16 u) {
  union { unsigned u; float f; } v; v.u = (unsigned)u << 16; return v.f;
}

// jax.nn.gelu default = tanh approximation
static __device__ __forceinline__ float gelu_f(float x) {
  float y = 0.7978845608028654f * (x + 0.044715f * x * x * x);
  float t = __expf(-2.0f * fabsf(y));
  float th = (1.0f - t) / (1.0f + t);
  th = (y < 0.0f) ? -th : th;
  return 0.5f * x * (1.0f + th);
}

static __device__ __forceinline__ void gl2lds16(const void* g, void* l) {
  __builtin_amdgcn_global_load_lds(
      (const __attribute__((address_space(1))) void*)g,
      (__attribute__((address_space(3))) void*)l, 16, 0, 0);
}

// ---------------- router: logits (fp64 accum), softmax, top-2 ----------------
__global__ __launch_bounds__(256) void k_router(
    const float* __restrict__ x, const float* __restrict__ gw,
    const float* __restrict__ gb, int* __restrict__ e_sel,
    float* __restrict__ gsel) {
  int wave = threadIdx.x >> 6, lane = threadIdx.x & 63;
  int t = blockIdx.x * 4 + wave;
  const float* xr = x + (size_t)t * DM;
  double acc[8] = {0,0,0,0,0,0,0,0};
  for (int d0 = lane * 4; d0 < DM; d0 += 256) {
    float4 xv = *(const float4*)(xr + d0);
    float xa[4] = {xv.x, xv.y, xv.z, xv.w};
    const float* g0 = gw + (size_t)d0 * NE;
#pragma unroll
    for (int dd = 0; dd < 4; ++dd)
#pragma unroll
      for (int e = 0; e < 8; ++e)
        acc[e] += (double)xa[dd] * (double)g0[dd * 8 + e];
  }
#pragma unroll
  for (int off = 32; off > 0; off >>= 1)
#pragma unroll
    for (int e = 0; e < 8; ++e)
      acc[e] += __shfl_down(acc[e], off, 64);
  if (lane == 0) {
    float l[8];
#pragma unroll
    for (int e = 0; e < 8; ++e) l[e] = (float)acc[e] + gb[e];
    int e0 = 0;
    for (int e = 1; e < 8; ++e) if (l[e] > l[e0]) e0 = e;
    int e1 = (e0 == 0) ? 1 : 0;
    for (int e = 0; e < 8; ++e) if (e != e0 && l[e] > l[e1]) e1 = e;
    float m = l[e0], s = 0.f, p[8];
    for (int e = 0; e < 8; ++e) { p[e] = expf(l[e] - m); s += p[e]; }
    e_sel[t] = e0; e_sel[TOK + t] = e1;
    gsel[t] = p[e0] / s; gsel[TOK + t] = p[e1] / s;
  }
}

// ------------- capacity assignment: serial cumsum per group, per-k ----------
__global__ void k_assign(const int* __restrict__ e_sel,
                         int* __restrict__ tok_slot, int* __restrict__ slot_tok) {
  int g = blockIdx.x;
  for (int i = threadIdx.x; i < NE * 32 * 2; i += 64) {
    int e = i >> 6, rem = i & 63, c = rem >> 1, k = rem & 1;
    slot_tok[((size_t)(e * MEP + g * 32 + c)) * 2 + k] = -1;
  }
  __syncthreads();
  if (threadIdx.x == 0) {
    int cnt[2][NE];
    for (int k = 0; k < 2; ++k) for (int e = 0; e < NE; ++e) cnt[k][e] = 0;
    for (int s = 0; s < GSZ; ++s) {
      int t = g * GSZ + s;
      for (int k = 0; k < 2; ++k) {
        int e = e_sel[k * TOK + t];
        int r = ++cnt[k][e];
        if (r <= CAPM) {
          int m = e * MEP + g * 32 + (r - 1);
          tok_slot[k * TOK + t] = m;
          slot_tok[(size_t)m * 2 + k] = t;
        } else tok_slot[k * TOK + t] = -1;
      }
    }
  }
}

// ------- exp_in[m,:] = bf16( x[t0] + x[t1] ); pad slots -> zeros ------------
__global__ __launch_bounds__(128) void k_build_expin(
    const float* __restrict__ x, const int* __restrict__ slot_tok,
    u16* __restrict__ exp_in) {
  int m = blockIdx.x;
  int t0 = slot_tok[(size_t)m * 2], t1 = slot_tok[(size_t)m * 2 + 1];
  int d = threadIdx.x * 8;
  float v[8] = {0,0,0,0,0,0,0,0};
  if (t0 >= 0) {
    const float4* p = (const float4*)(x + (size_t)t0 * DM + d);
    float4 a = p[0], b = p[1];
    v[0]+=a.x; v[1]+=a.y; v[2]+=a.z; v[3]+=a.w;
    v[4]+=b.x; v[5]+=b.y; v[6]+=b.z; v[7]+=b.w;
  }
  if (t1 >= 0) {
    const float4* p = (const float4*)(x + (size_t)t1 * DM + d);
    float4 a = p[0], b = p[1];
    v[0]+=a.x; v[1]+=a.y; v[2]+=a.z; v[3]+=a.w;
    v[4]+=b.x; v[5]+=b.y; v[6]+=b.z; v[7]+=b.w;
  }
  ushort4 o0, o1;
  o0.x=f2b(v[0]); o0.y=f2b(v[1]); o0.z=f2b(v[2]); o0.w=f2b(v[3]);
  o1.x=f2b(v[4]); o1.y=f2b(v[5]); o1.z=f2b(v[6]); o1.w=f2b(v[7]);
  *(ushort4*)(exp_in + (size_t)m * DM + d) = o0;
  *(ushort4*)(exp_in + (size_t)m * DM + d + 4) = o1;
}

// ------------------------------ fp32 -> bf16 --------------------------------
__global__ __launch_bounds__(256) void k_cast_bf16(
    const float* __restrict__ in, u16* __restrict__ out, size_t n) {
  size_t i = ((size_t)blockIdx.x * 256 + threadIdx.x) * 4;
  if (i >= n) return;
  float4 v = *(const float4*)(in + i);
  ushort4 o; o.x=f2b(v.x); o.y=f2b(v.y); o.z=f2b(v.z); o.w=f2b(v.w);
  *(ushort4*)(out + i) = o;
}

// --------- transpose+cast: in(k,n) at in[k*rs+n] fp32 -> out[n*K+k] bf16 ----
__global__ __launch_bounds__(256) void k_transpose(
    const float* __restrict__ in, u16* __restrict__ out,
    int K, int N, int rs) {
  __shared__ float tile[32][33];
  int k0 = blockIdx.x * 32, n0 = blockIdx.y * 32;
  int tx = threadIdx.x & 31, ty = threadIdx.x >> 5;
#pragma unroll
  for (int i = 0; i < 4; ++i)
    tile[ty + i * 8][tx] = in[(size_t)(k0 + ty + i * 8) * rs + n0 + tx];
  __syncthreads();
#pragma unroll
  for (int i = 0; i < 4; ++i) {
    int n = ty + i * 8;
    out[(size_t)(n0 + n) * K + k0 + tx] = f2b(tile[tx][n]);
  }
}

// ---- 256x256 bf16 MFMA GEMM: 8-phase + read-ahead register pipeline --------
// Same barrier/ring/swizzle skeleton as round 9 (verified), but each phase
// region issues the ds_reads needed by the NEXT phase before its own MFMA
// burst -> DS pipe executes under the MFMA burst instead of serializing.
// vmcnt ledger (re-derived for one-phase-early reads, >=2-phase lead):
//   P0: vmcnt(2)  forces Ah1(t)       (read in P1 region)
//   P1: (none)
//   P2: vmcnt(2)  forces Ah0,Bh0(t+1) (read in P3 region)
//   P3: vmcnt(2)  forces Bh1(t+1)     (read in P0(t+1) region)
// Stages during tile t (for t+1): P0->Ah0, P1->Bh0, P2->Bh1, P3->Ah1.

#define SP1() __builtin_amdgcn_s_setprio(1);
#define SP0() __builtin_amdgcn_s_setprio(0);
#define BAR() __builtin_amdgcn_s_barrier();
#define VM2() asm volatile("s_waitcnt vmcnt(2)" ::: "memory");
#define VM0() asm volatile("s_waitcnt vmcnt(0)" ::: "memory");

#define STG(gp, ld, lds) \
  gl2lds16((gp) + (size_t)srow * (ld) + scol, (lds) + sdst); \
  gl2lds16((gp) + (size_t)(srow + 64) * (ld) + scol, (lds) + 4096 + sdst);

// A-frag rows: (mi*2+wr)*16+la15 -> elem off = offAk[k2] + mi*2048
#define RD_A(DST, SLOT) \
  _Pragma("unroll") for (int k2 = 0; k2 < 2; ++k2) \
    _Pragma("unroll") for (int mi = 0; mi < 4; ++mi) \
      DST[k2][mi] = *(const bf16x8*)(&HA[SLOT][0] + offAk[k2] + mi * 2048);

// B-frag rows: (ni*4+wc)*16+la15 -> elem off = offBk[k2] + ni*4096
#define RD_B(DST, SLOT) \
  _Pragma("unroll") for (int k2 = 0; k2 < 2; ++k2) \
    _Pragma("unroll") for (int ni = 0; ni < 2; ++ni) \
      DST[k2][ni] = *(const bf16x8*)(&HB[SLOT][0] + offBk[k2] + ni * 4096);

#define MMA(AM, BM, MOFF, NOFF) \
  _Pragma("unroll") for (int k2 = 0; k2 < 2; ++k2) \
    _Pragma("unroll") for (int mi = 0; mi < 4; ++mi) \
      _Pragma("unroll") for (int ni = 0; ni < 2; ++ni) \
        acc[mi + MOFF][ni + NOFF] = __builtin_amdgcn_mfma_f32_16x16x32_bf16( \
            AM[k2][mi], BM[k2][ni], acc[mi + MOFF][ni + NOFF], 0, 0, 0);

// entering each tile: aC=Ah0(t), bA=Bh0(t) already in regs (read in prior P3)
#define TILE(T, SA0, SA1, SB0, SB1, DA0, DA1, DB0, DB1) { \
  const u16* An = Ab + ((T) + 1) * 64; \
  const u16* Bn = Bb + ((T) + 1) * 64; \
  /* P0: rd bB<-Bh1(t); stg Ah0(t+1); MM q0 = aC x bA */ \
  RD_B(bB, SB1); STG(An, lda, &HA[DA0][0]); \
  SP1(); MMA(aC, bA, 0, 0); SP0(); \
  VM2(); BAR(); \
  /* P1: rd aN<-Ah1(t); stg Bh0(t+1); MM q1 = aC x bB */ \
  RD_A(aN, SA1); STG(Bn, ldb, &HB[DB0][0]); \
  SP1(); MMA(aC, bB, 0, 2); SP0(); \
  BAR(); \
  /* P2: stg Bh1(t+1); MM q2 = aN x bB */ \
  STG(Bn + (size_t)128 * ldb, ldb, &HB[DB1][0]); \
  SP1(); MMA(aN, bB, 4, 2); SP0(); \
  VM2(); BAR(); \
  /* P3: rd aC<-Ah0(t+1), bA<-Bh0(t+1); stg Ah1(t+1); MM q3 = aN x bA(old) */ \
  RD_A(aC, DA0); STG(An + (size_t)128 * lda, lda, &HA[DA1][0]); \
  SP1(); MMA(aN, bA, 4, 0); SP0(); \
  RD_B(bA, DB0); \
  VM2(); BAR(); \
}

// last tile: nothing staged; drain remaining (Ah1) with vmcnt(0) at P0 end
#define TILE_LAST(SA0, SA1, SB0, SB1) { \
  RD_B(bB, SB1); \
  SP1(); MMA(aC, bA, 0, 0); SP0(); \
  VM0(); BAR(); \
  RD_A(aN, SA1); \
  SP1(); MMA(aC, bB, 0, 2); \
  MMA(aN, bB, 4, 2); MMA(aN, bA, 4, 0); SP0(); \
}

template <int EPI>
__global__ __launch_bounds__(512, 2) void k_gemm8p(
    const u16* __restrict__ A, size_t sAe, int lda,
    const u16* __restrict__ B, size_t sBe, int ldb,
    void* __restrict__ Cv, size_t sCe, int ldc,
    const float* __restrict__ bias, int sBiasE, int K, int gx, int gy) {
  __shared__ __align__(16) u16 HA[4][128 * 64];
  __shared__ __align__(16) u16 HB[4][128 * 64];
  const int tid = threadIdx.x;
  const int lane = tid & 63, wid = tid >> 6;
  const int wr = wid >> 2, wc = wid & 3;
  const int la15 = lane & 15, hi = lane >> 4;

  // T1: bijective XCD-chunked remap of 1D grid (gridDim.x % 8 == 0)
  int nwg = gridDim.x, per = nwg >> 3;
  int wg = (blockIdx.x & 7) * per + (blockIdx.x >> 3);
  int bx = wg % gx, tmp = wg / gx;
  int by = tmp % gy, z = tmp / gy;

  const u16* Ab = A + (size_t)z * sAe + (size_t)(bx * 256) * lda;
  const u16* Bb = B + (size_t)z * sBe + (size_t)(by * 256) * ldb;

  // swizzle term is row16-aligned -> depends only on la15&7 (not mi/ni)
  int offAk[2], offBk[2];
#pragma unroll
  for (int k2 = 0; k2 < 2; ++k2) {
    int sw = (((k2 * 4 + hi) ^ (la15 & 7)) << 3);
    offAk[k2] = (wr * 16 + la15) * 64 + sw;
    offBk[k2] = (wc * 16 + la15) * 64 + sw;
  }
  // per-lane stage offsets (inverse-swizzled global src, linear LDS dest)
  const int srow = tid >> 3;
  const int scol = (((tid & 7) ^ (srow & 7)) << 3);
  const int sdst = (tid & ~63) * 8;

  f32x4 acc[8][4] = {};
  const int NT = K >> 6;

  bf16x8 aC[2][4], aN[2][4], bA[2][2], bB[2][2];

  // prologue: stage tile 0 halves; force Ah0,Bh0,Bh1 (keep Ah1 in flight)
  STG(Ab, lda, &HA[0][0]);
  STG(Bb, ldb, &HB[0][0]);
  STG(Bb + (size_t)128 * ldb, ldb, &HB[1][0]);
  STG(Ab + (size_t)128 * lda, lda, &HA[1][0]);
  VM2(); BAR();
  RD_A(aC, 0); RD_B(bA, 0);

  for (int t = 0; t + 2 < NT; t += 2) {
    TILE(t,     0, 1, 0, 1, 2, 3, 2, 3);
    TILE(t + 1, 2, 3, 2, 3, 0, 1, 0, 1);
  }
  TILE(NT - 2, 0, 1, 0, 1, 2, 3, 2, 3);
  TILE_LAST(2, 3, 2, 3);

  // epilogue (strided mapping)
  const int hi4 = hi << 2;
#pragma unroll
  for (int ni = 0; ni < 4; ++ni) {
    int col = by * 256 + (ni * 4 + wc) * 16 + la15;
    float bv = bias[(size_t)z * sBiasE + col];
#pragma unroll
    for (int mi = 0; mi < 8; ++mi) {
      int row0 = bx * 256 + (mi * 2 + wr) * 16 + hi4;
      f32x4 v = acc[mi][ni];
#pragma unroll
      for (int j = 0; j < 4; ++j) {
        int row = row0 + j;
        float val = v[j] + bv;
        if (EPI == 0)
          ((u16*)Cv)[(size_t)z * sCe + (size_t)row * ldc + col] = f2b(gelu_f(val));
        else if (EPI == 1)
          ((u16*)Cv)[(size_t)z * sCe + (size_t)row * ldc + col] = f2b(val);
        else
          ((float*)Cv)[(size_t)z * sCe + (size_t)row * ldc + col] = val;
      }
    }
  }
}

// ------------------ out[t] += sum_k gate_k * eo[slot_k] (eo bf16) -----------
__global__ __launch_bounds__(256) void k_combine(
    const int* __restrict__ tok_slot, const float* __restrict__ gsel,
    const u16* __restrict__ eo, float* __restrict__ out) {
  int t = blockIdx.x;
  int d = threadIdx.x * 4;
  float4 v = *(float4*)(out + (size_t)t * DM + d);
#pragma unroll
  for (int k = 0; k < 2; ++k) {
    int m = tok_slot[k * TOK + t];
    if (m >= 0) {
      float g = gsel[k * TOK + t];
      ushort4 e = *(const ushort4*)(eo + (size_t)m * DM + d);
      v.x += g * b2f(e.x); v.y += g * b2f(e.y);
      v.z += g * b2f(e.z); v.w += g * b2f(e.w);
    }
  }
  *(float4*)(out + (size_t)t * DM + d) = v;
}

__global__ void k_report(float* out, float code) { out[0] = code; }

extern "C" void kernel_launch(void* const* d_in, const int* in_sizes, int n_in,
                              void* d_out, int out_size, void* d_ws, size_t ws_size,
                              hipStream_t stream) {
  (void)in_sizes; (void)n_in;
  const float* x     = (const float*)d_in[0];
  const float* gw    = (const float*)d_in[1];
  const float* gb    = (const float*)d_in[2];
  const float* keys  = (const float*)d_in[3];
  const float* keyb  = (const float*)d_in[4];
  const float* vals  = (const float*)d_in[5];
  const float* valb  = (const float*)d_in[6];
  const float* skey  = (const float*)d_in[7];
  const float* skeyb = (const float*)d_in[8];
  const float* sval  = (const float*)d_in[9];
  const float* svalb = (const float*)d_in[10];
  float* out = (float*)d_out;

  char* ws = (char*)d_ws;
  size_t off = 0;
  auto alloc = [&](size_t bytes) -> char* {
    char* p = ws + off; off += (bytes + 255) & ~(size_t)255; return p;
  };
  int*   e_sel    = (int*)  alloc(2 * TOK * 4);
  float* gsel     = (float*)alloc(2 * TOK * 4);
  int*   tok_slot = (int*)  alloc(2 * TOK * 4);
  int*   slot_tok = (int*)  alloc((size_t)NE * MEP * 2 * 4);

  size_t off_r1 = off;              // union: {xb,skT,svT,exp_in} then eo(bf16)
  u16* xb     = (u16*)alloc((size_t)TOK * DM * 2);
  u16* skT    = (u16*)alloc((size_t)HD * DM * 2);
  u16* svT    = (u16*)alloc((size_t)DM * HD * 2);
  u16* exp_in = (u16*)alloc((size_t)NE * MEP * DM * 2);
  u16* eo = (u16*)(ws + off_r1);
  size_t eo_end = off_r1 + (size_t)NE * MEP * DM * 2;
  if (eo_end > off) off = eo_end;

  u16* keysT = (u16*)alloc((size_t)NE * HD * DM * 2);
  u16* valsT = (u16*)alloc((size_t)NE * DM * HD * 2);

  size_t sh_b = (size_t)TOK * HD * 2;          // union: sh then h
  size_t h_b  = (size_t)NE * MEP * HD * 2;
  u16* sh = (u16*)(ws + off);
  u16* h  = (u16*)(ws + off);
  size_t need = off + (sh_b > h_b ? sh_b : h_b);

  if (need > ws_size) {                        // sentinel: out[0] = -available MB
    hipMemsetAsync(d_out, 0, (size_t)out_size * 4, stream);
    k_report<<<1, 1, 0, stream>>>(out, -(float)(ws_size >> 20));
    return;
  }

  // routing + assignment + dispatch gather
  k_router<<<TOK / 4, 256, 0, stream>>>(x, gw, gb, e_sel, gsel);
  k_assign<<<NG, 64, 0, stream>>>(e_sel, tok_slot, slot_tok);
  k_build_expin<<<NE * MEP, 128, 0, stream>>>(x, slot_tok, exp_in);

  // bf16 casts / weight transposes
  k_cast_bf16<<<(TOK * DM / 4) / 256, 256, 0, stream>>>(x, xb, (size_t)TOK * DM);
  k_transpose<<<dim3(DM / 32, HD / 32), 256, 0, stream>>>(skey, skT, DM, HD, HD);
  k_transpose<<<dim3(HD / 32, DM / 32), 256, 0, stream>>>(sval, svT, HD, DM, DM);
  for (int e = 0; e < NE; ++e) {
    k_transpose<<<dim3(DM / 32, HD / 32), 256, 0, stream>>>(
        keys + (size_t)e * HD, keysT + (size_t)e * HD * DM, DM, HD, NE * HD);
    k_transpose<<<dim3(HD / 32, DM / 32), 256, 0, stream>>>(
        vals + (size_t)e * DM, valsT + (size_t)e * DM * HD, HD, DM, NE * DM);
  }

  // shared expert: sh = gelu(xb @ skT + skeyb); out = sh @ svT + svalb
  k_gemm8p<0><<<(TOK/256)*(HD/256), 512, 0, stream>>>(
      xb, 0, DM, skT, 0, DM, sh, 0, HD, skeyb, 0, DM, TOK/256, HD/256);
  k_gemm8p<2><<<(TOK/256)*(DM/256), 512, 0, stream>>>(
      sh, 0, HD, svT, 0, HD, out, 0, DM, svalb, 0, HD, TOK/256, DM/256);

  // MoE experts
  k_gemm8p<0><<<(MEP/256)*(HD/256)*NE, 512, 0, stream>>>(
      exp_in, (size_t)MEP * DM, DM, keysT, (size_t)HD * DM, DM,
      h, (size_t)MEP * HD, HD, keyb, HD, DM, MEP/256, HD/256);
  k_gemm8p<1><<<(MEP/256)*(DM/256)*NE, 512, 0, stream>>>(
      h, (size_t)MEP * HD, HD, valsT, (size_t)DM * HD, HD,
      eo, (size_t)MEP * DM, DM, valb, DM, HD, MEP/256, DM/256);

  // combine: out += gate * eo[slot]
  k_combine<<<TOK, 256, 0, stream>>>(tok_slot, gsel, eo, out);
}

// Round 12
// 1223.738 us; speedup vs baseline: 1.5604x; 1.5604x over previous
//
#include <hip/hip_runtime.h>
#include <hip/hip_bf16.h>

typedef unsigned short u16;
typedef __attribute__((ext_vector_type(8))) __bf16 bf16x8;
typedef __attribute__((ext_vector_type(4))) float f32x4;

#define TOK 16384
#define DM  1024
#define HD  4096
#define NE  8
#define NG  128
#define GSZ 128
#define CAPM 31               // usable slots per (group, expert)
#define MEP (NG*32)           // 4096 padded rows per expert (slot 31 = zero pad)

static __device__ __forceinline__ u16 f2b(float f) {
  union { float f; unsigned u; } v; v.f = f;
  unsigned r = v.u + 0x7fffu + ((v.u >> 16) & 1u);
  return (u16)(r >> 16);
}
static __device__ __forceinline__ float b2f(u16 u) {
  union { unsigned u; float f; } v; v.u = (unsigned)u << 16; return v.f;
}

// jax.nn.gelu default = tanh approximation
static __device__ __forceinline__ float gelu_f(float x) {
  float y = 0.7978845608028654f * (x + 0.044715f * x * x * x);
  float t = __expf(-2.0f * fabsf(y));
  float th = (1.0f - t) / (1.0f + t);
  th = (y < 0.0f) ? -th : th;
  return 0.5f * x * (1.0f + th);
}

static __device__ __forceinline__ void gl2lds16(const void* g, void* l) {
  __builtin_amdgcn_global_load_lds(
      (const __attribute__((address_space(1))) void*)g,
      (__attribute__((address_space(3))) void*)l, 16, 0, 0);
}

// ---------------- router: logits (fp64 accum), softmax, top-2 ----------------
__global__ __launch_bounds__(256) void k_router(
    const float* __restrict__ x, const float* __restrict__ gw,
    const float* __restrict__ gb, int* __restrict__ e_sel,
    float* __restrict__ gsel) {
  int wave = threadIdx.x >> 6, lane = threadIdx.x & 63;
  int t = blockIdx.x * 4 + wave;
  const float* xr = x + (size_t)t * DM;
  double acc[8] = {0,0,0,0,0,0,0,0};
  for (int d0 = lane * 4; d0 < DM; d0 += 256) {
    float4 xv = *(const float4*)(xr + d0);
    float xa[4] = {xv.x, xv.y, xv.z, xv.w};
    const float* g0 = gw + (size_t)d0 * NE;
#pragma unroll
    for (int dd = 0; dd < 4; ++dd)
#pragma unroll
      for (int e = 0; e < 8; ++e)
        acc[e] += (double)xa[dd] * (double)g0[dd * 8 + e];
  }
#pragma unroll
  for (int off = 32; off > 0; off >>= 1)
#pragma unroll
    for (int e = 0; e < 8; ++e)
      acc[e] += __shfl_down(acc[e], off, 64);
  if (lane == 0) {
    float l[8];
#pragma unroll
    for (int e = 0; e < 8; ++e) l[e] = (float)acc[e] + gb[e];
    int e0 = 0;
    for (int e = 1; e < 8; ++e) if (l[e] > l[e0]) e0 = e;
    int e1 = (e0 == 0) ? 1 : 0;
    for (int e = 0; e < 8; ++e) if (e != e0 && l[e] > l[e1]) e1 = e;
    float m = l[e0], s = 0.f, p[8];
    for (int e = 0; e < 8; ++e) { p[e] = expf(l[e] - m); s += p[e]; }
    e_sel[t] = e0; e_sel[TOK + t] = e1;
    gsel[t] = p[e0] / s; gsel[TOK + t] = p[e1] / s;
  }
}

// ------------- capacity assignment: serial cumsum per group, per-k ----------
__global__ void k_assign(const int* __restrict__ e_sel,
                         int* __restrict__ tok_slot, int* __restrict__ slot_tok) {
  int g = blockIdx.x;
  for (int i = threadIdx.x; i < NE * 32 * 2; i += 64) {
    int e = i >> 6, rem = i & 63, c = rem >> 1, k = rem & 1;
    slot_tok[((size_t)(e * MEP + g * 32 + c)) * 2 + k] = -1;
  }
  __syncthreads();
  if (threadIdx.x == 0) {
    int cnt[2][NE];
    for (int k = 0; k < 2; ++k) for (int e = 0; e < NE; ++e) cnt[k][e] = 0;
    for (int s = 0; s < GSZ; ++s) {
      int t = g * GSZ + s;
      for (int k = 0; k < 2; ++k) {
        int e = e_sel[k * TOK + t];
        int r = ++cnt[k][e];
        if (r <= CAPM) {
          int m = e * MEP + g * 32 + (r - 1);
          tok_slot[k * TOK + t] = m;
          slot_tok[(size_t)m * 2 + k] = t;
        } else tok_slot[k * TOK + t] = -1;
      }
    }
  }
}

// ------- exp_in[m,:] = bf16( x[t0] + x[t1] ); pad slots -> zeros ------------
__global__ __launch_bounds__(128) void k_build_expin(
    const float* __restrict__ x, const int* __restrict__ slot_tok,
    u16* __restrict__ exp_in) {
  int m = blockIdx.x;
  int t0 = slot_tok[(size_t)m * 2], t1 = slot_tok[(size_t)m * 2 + 1];
  int d = threadIdx.x * 8;
  float v[8] = {0,0,0,0,0,0,0,0};
  if (t0 >= 0) {
    const float4* p = (const float4*)(x + (size_t)t0 * DM + d);
    float4 a = p[0], b = p[1];
    v[0]+=a.x; v[1]+=a.y; v[2]+=a.z; v[3]+=a.w;
    v[4]+=b.x; v[5]+=b.y; v[6]+=b.z; v[7]+=b.w;
  }
  if (t1 >= 0) {
    const float4* p = (const float4*)(x + (size_t)t1 * DM + d);
    float4 a = p[0], b = p[1];
    v[0]+=a.x; v[1]+=a.y; v[2]+=a.z; v[3]+=a.w;
    v[4]+=b.x; v[5]+=b.y; v[6]+=b.z; v[7]+=b.w;
  }
  ushort4 o0, o1;
  o0.x=f2b(v[0]); o0.y=f2b(v[1]); o0.z=f2b(v[2]); o0.w=f2b(v[3]);
  o1.x=f2b(v[4]); o1.y=f2b(v[5]); o1.z=f2b(v[6]); o1.w=f2b(v[7]);
  *(ushort4*)(exp_in + (size_t)m * DM + d) = o0;
  *(ushort4*)(exp_in + (size_t)m * DM + d + 4) = o1;
}

// ------------------------------ fp32 -> bf16 --------------------------------
__global__ __launch_bounds__(256) void k_cast_bf16(
    const float* __restrict__ in, u16* __restrict__ out, size_t n) {
  size_t i = ((size_t)blockIdx.x * 256 + threadIdx.x) * 4;
  if (i >= n) return;
  float4 v = *(const float4*)(in + i);
  ushort4 o; o.x=f2b(v.x); o.y=f2b(v.y); o.z=f2b(v.z); o.w=f2b(v.w);
  *(ushort4*)(out + i) = o;
}

// --------- transpose+cast: in(k,n) at in[k*rs+n] fp32 -> out[n*K+k] bf16 ----
__global__ __launch_bounds__(256) void k_transpose(
    const float* __restrict__ in, u16* __restrict__ out,
    int K, int N, int rs) {
  __shared__ float tile[32][33];
  int k0 = blockIdx.x * 32, n0 = blockIdx.y * 32;
  int tx = threadIdx.x & 31, ty = threadIdx.x >> 5;
#pragma unroll
  for (int i = 0; i < 4; ++i)
    tile[ty + i * 8][tx] = in[(size_t)(k0 + ty + i * 8) * rs + n0 + tx];
  __syncthreads();
#pragma unroll
  for (int i = 0; i < 4; ++i) {
    int n = ty + i * 8;
    out[(size_t)(n0 + n) * K + k0 + tx] = f2b(tile[tx][n]);
  }
}

// ---- 256x256 bf16 MFMA GEMM, 8-phase counted-vmcnt, ONE barrier/phase ------
// Round-9 structure (verified correct, 375us) minus the mid-phase barrier:
// each phase = {ds_read frags, stage-issue, setprio1, MFMA, setprio0,
// vmcnt(4), barrier}. Waves drift within the region -> one wave's ds_reads
// run on the DS pipe under another wave's MFMA burst (inter-wave overlap)
// with ZERO extra live registers (round 11's cross-barrier reg pipeline
// spilled: WRITE_SIZE 262->873MB). Hazards: RAW gl2lds->read enforced by
// unchanged vmcnt(4)+end-barrier ledger (4-phase stage-to-read separation);
// WAR read->restage safe (reads consumed by same-region MFMA lgkm waits,
// >=2 end-barriers before slot reuse).

#define PH_MID() \
  __builtin_amdgcn_s_setprio(1);

#define PH_END() \
  __builtin_amdgcn_s_setprio(0); \
  asm volatile("s_waitcnt vmcnt(4)" ::: "memory"); \
  __builtin_amdgcn_s_barrier();

#define PH_END0() \
  __builtin_amdgcn_s_setprio(0); \
  asm volatile("s_waitcnt vmcnt(0)" ::: "memory"); \
  __builtin_amdgcn_s_barrier();

#define PH_ENDN() \
  __builtin_amdgcn_s_setprio(0); \
  __builtin_amdgcn_s_barrier();

#define STG(gp, ld, lds) \
  gl2lds16((gp) + (size_t)srow * (ld) + scol, (lds) + sdst); \
  gl2lds16((gp) + (size_t)(srow + 64) * (ld) + scol, (lds) + 4096 + sdst);

#define RD_A(SLOT) \
  _Pragma("unroll") for (int k2 = 0; k2 < 2; ++k2) \
    _Pragma("unroll") for (int mi = 0; mi < 4; ++mi) \
      a[k2][mi] = *(const bf16x8*)(&HA[SLOT][0] + offA[k2][mi]);

#define RD_BA(SLOT) \
  _Pragma("unroll") for (int k2 = 0; k2 < 2; ++k2) \
    _Pragma("unroll") for (int ni = 0; ni < 2; ++ni) \
      bA[k2][ni] = *(const bf16x8*)(&HB[SLOT][0] + offB[k2][ni]);

#define RD_BB(SLOT) \
  _Pragma("unroll") for (int k2 = 0; k2 < 2; ++k2) \
    _Pragma("unroll") for (int ni = 0; ni < 2; ++ni) \
      bB[k2][ni] = *(const bf16x8*)(&HB[SLOT][0] + offB[k2][ni]);

#define MM(BM, MOFF, NOFF) \
  _Pragma("unroll") for (int k2 = 0; k2 < 2; ++k2) \
    _Pragma("unroll") for (int mi = 0; mi < 4; ++mi) \
      _Pragma("unroll") for (int ni = 0; ni < 2; ++ni) \
        acc[mi + MOFF][ni + NOFF] = __builtin_amdgcn_mfma_f32_16x16x32_bf16( \
            a[k2][mi], BM[k2][ni], acc[mi + MOFF][ni + NOFF], 0, 0, 0);

// full tile with staging of tile T+1 (slots constant via macro args)
#define TILE(T, SA0, SA1, SB0, SB1, DA0, DA1, DB0, DB1) { \
  const u16* An = Ab + ((T) + 1) * 64; \
  const u16* Bn = Bb + ((T) + 1) * 64; \
  RD_A(SA0); RD_BA(SB0); \
  STG(An, lda, &HA[DA0][0]); \
  PH_MID(); MM(bA, 0, 0); PH_END(); \
  RD_BB(SB1); \
  STG(Bn, ldb, &HB[DB0][0]); \
  PH_MID(); MM(bB, 0, 2); PH_END(); \
  RD_A(SA1); \
  STG(Bn + (size_t)128 * ldb, ldb, &HB[DB1][0]); \
  PH_MID(); MM(bB, 4, 2); PH_END(); \
  STG(An + (size_t)128 * lda, lda, &HA[DA1][0]); \
  PH_MID(); MM(bA, 4, 0); PH_END(); \
}

// last tile: nothing staged; P0 drains vmcnt fully (guarantees its halves)
#define TILE_LAST(SA0, SA1, SB0, SB1) { \
  RD_A(SA0); RD_BA(SB0); \
  PH_MID(); MM(bA, 0, 0); PH_END0(); \
  RD_BB(SB1); \
  PH_MID(); MM(bB, 0, 2); PH_ENDN(); \
  RD_A(SA1); \
  PH_MID(); MM(bB, 4, 2); PH_ENDN(); \
  PH_MID(); MM(bA, 4, 0); PH_ENDN(); \
}

template <int EPI>
__global__ __launch_bounds__(512, 2) void k_gemm8p(
    const u16* __restrict__ A, size_t sAe, int lda,
    const u16* __restrict__ B, size_t sBe, int ldb,
    void* __restrict__ Cv, size_t sCe, int ldc,
    const float* __restrict__ bias, int sBiasE, int K, int gx, int gy) {
  __shared__ __align__(16) u16 HA[4][128 * 64];
  __shared__ __align__(16) u16 HB[4][128 * 64];
  const int tid = threadIdx.x;
  const int lane = tid & 63, wid = tid >> 6;
  const int wr = wid >> 2, wc = wid & 3;
  const int la15 = lane & 15, hi = lane >> 4;

  // T1: bijective XCD-chunked remap of 1D grid (gridDim.x % 8 == 0)
  int nwg = gridDim.x, per = nwg >> 3;
  int wg = (blockIdx.x & 7) * per + (blockIdx.x >> 3);
  int bx = wg % gx, tmp = wg / gx;
  int by = tmp % gy, z = tmp / gy;

  const u16* Ab = A + (size_t)z * sAe + (size_t)(bx * 256) * lda;
  const u16* Bb = B + (size_t)z * sBe + (size_t)(by * 256) * ldb;

  // per-lane ds_read element offsets (identical for every ring slot)
  int offA[2][4], offB[2][2];
#pragma unroll
  for (int k2 = 0; k2 < 2; ++k2) {
    int sl = k2 * 4 + hi;
#pragma unroll
    for (int mi = 0; mi < 4; ++mi) {
      int r = (mi * 2 + wr) * 16 + la15;
      offA[k2][mi] = r * 64 + ((sl ^ (r & 7)) << 3);
    }
#pragma unroll
    for (int ni = 0; ni < 2; ++ni) {
      int r = (ni * 4 + wc) * 16 + la15;
      offB[k2][ni] = r * 64 + ((sl ^ (r & 7)) << 3);
    }
  }
  // per-lane stage offsets (inverse-swizzled global src, linear LDS dest)
  const int srow = tid >> 3;
  const int scol = (((tid & 7) ^ (srow & 7)) << 3);
  const int sdst = (tid & ~63) * 8;

  f32x4 acc[8][4] = {};
  const int NT = K >> 6;

  bf16x8 a[2][4], bA[2][2], bB[2][2];

  // prologue: tile 0 (4 halves), full drain once
  STG(Ab, lda, &HA[0][0]);
  STG(Bb, ldb, &HB[0][0]);
  STG(Bb + (size_t)128 * ldb, ldb, &HB[1][0]);
  STG(Ab + (size_t)128 * lda, lda, &HA[1][0]);
  asm volatile("s_waitcnt vmcnt(0)" ::: "memory");
  __builtin_amdgcn_s_barrier();

  for (int t = 0; t + 2 < NT; t += 2) {
    TILE(t,     0, 1, 0, 1, 2, 3, 2, 3);
    TILE(t + 1, 2, 3, 2, 3, 0, 1, 0, 1);
  }
  TILE(NT - 2, 0, 1, 0, 1, 2, 3, 2, 3);
  TILE_LAST(2, 3, 2, 3);

  // epilogue (strided mapping)
  const int hi4 = hi << 2;
#pragma unroll
  for (int ni = 0; ni < 4; ++ni) {
    int col = by * 256 + (ni * 4 + wc) * 16 + la15;
    float bv = bias[(size_t)z * sBiasE + col];
#pragma unroll
    for (int mi = 0; mi < 8; ++mi) {
      int row0 = bx * 256 + (mi * 2 + wr) * 16 + hi4;
      f32x4 v = acc[mi][ni];
#pragma unroll
      for (int j = 0; j < 4; ++j) {
        int row = row0 + j;
        float val = v[j] + bv;
        if (EPI == 0)
          ((u16*)Cv)[(size_t)z * sCe + (size_t)row * ldc + col] = f2b(gelu_f(val));
        else if (EPI == 1)
          ((u16*)Cv)[(size_t)z * sCe + (size_t)row * ldc + col] = f2b(val);
        else
          ((float*)Cv)[(size_t)z * sCe + (size_t)row * ldc + col] = val;
      }
    }
  }
}

// ------------------ out[t] += sum_k gate_k * eo[slot_k] (eo bf16) -----------
__global__ __launch_bounds__(256) void k_combine(
    const int* __restrict__ tok_slot, const float* __restrict__ gsel,
    const u16* __restrict__ eo, float* __restrict__ out) {
  int t = blockIdx.x;
  int d = threadIdx.x * 4;
  float4 v = *(float4*)(out + (size_t)t * DM + d);
#pragma unroll
  for (int k = 0; k < 2; ++k) {
    int m = tok_slot[k * TOK + t];
    if (m >= 0) {
      float g = gsel[k * TOK + t];
      ushort4 e = *(const ushort4*)(eo + (size_t)m * DM + d);
      v.x += g * b2f(e.x); v.y += g * b2f(e.y);
      v.z += g * b2f(e.z); v.w += g * b2f(e.w);
    }
  }
  *(float4*)(out + (size_t)t * DM + d) = v;
}

__global__ void k_report(float* out, float code) { out[0] = code; }

extern "C" void kernel_launch(void* const* d_in, const int* in_sizes, int n_in,
                              void* d_out, int out_size, void* d_ws, size_t ws_size,
                              hipStream_t stream) {
  (void)in_sizes; (void)n_in;
  const float* x     = (const float*)d_in[0];
  const float* gw    = (const float*)d_in[1];
  const float* gb    = (const float*)d_in[2];
  const float* keys  = (const float*)d_in[3];
  const float* keyb  = (const float*)d_in[4];
  const float* vals  = (const float*)d_in[5];
  const float* valb  = (const float*)d_in[6];
  const float* skey  = (const float*)d_in[7];
  const float* skeyb = (const float*)d_in[8];
  const float* sval  = (const float*)d_in[9];
  const float* svalb = (const float*)d_in[10];
  float* out = (float*)d_out;

  char* ws = (char*)d_ws;
  size_t off = 0;
  auto alloc = [&](size_t bytes) -> char* {
    char* p = ws + off; off += (bytes + 255) & ~(size_t)255; return p;
  };
  int*   e_sel    = (int*)  alloc(2 * TOK * 4);
  float* gsel     = (float*)alloc(2 * TOK * 4);
  int*   tok_slot = (int*)  alloc(2 * TOK * 4);
  int*   slot_tok = (int*)  alloc((size_t)NE * MEP * 2 * 4);

  size_t off_r1 = off;              // union: {xb,skT,svT,exp_in} then eo(bf16)
  u16* xb     = (u16*)alloc((size_t)TOK * DM * 2);
  u16* skT    = (u16*)alloc((size_t)HD * DM * 2);
  u16* svT    = (u16*)alloc((size_t)DM * HD * 2);
  u16* exp_in = (u16*)alloc((size_t)NE * MEP * DM * 2);
  u16* eo = (u16*)(ws + off_r1);
  size_t eo_end = off_r1 + (size_t)NE * MEP * DM * 2;
  if (eo_end > off) off = eo_end;

  u16* keysT = (u16*)alloc((size_t)NE * HD * DM * 2);
  u16* valsT = (u16*)alloc((size_t)NE * DM * HD * 2);

  size_t sh_b = (size_t)TOK * HD * 2;          // union: sh then h
  size_t h_b  = (size_t)NE * MEP * HD * 2;
  u16* sh = (u16*)(ws + off);
  u16* h  = (u16*)(ws + off);
  size_t need = off + (sh_b > h_b ? sh_b : h_b);

  if (need > ws_size) {                        // sentinel: out[0] = -available MB
    hipMemsetAsync(d_out, 0, (size_t)out_size * 4, stream);
    k_report<<<1, 1, 0, stream>>>(out, -(float)(ws_size >> 20));
    return;
  }

  // routing + assignment + dispatch gather
  k_router<<<TOK / 4, 256, 0, stream>>>(x, gw, gb, e_sel, gsel);
  k_assign<<<NG, 64, 0, stream>>>(e_sel, tok_slot, slot_tok);
  k_build_expin<<<NE * MEP, 128, 0, stream>>>(x, slot_tok, exp_in);

  // bf16 casts / weight transposes
  k_cast_bf16<<<(TOK * DM / 4) / 256, 256, 0, stream>>>(x, xb, (size_t)TOK * DM);
  k_transpose<<<dim3(DM / 32, HD / 32), 256, 0, stream>>>(skey, skT, DM, HD, HD);
  k_transpose<<<dim3(HD / 32, DM / 32), 256, 0, stream>>>(sval, svT, HD, DM, DM);
  for (int e = 0; e < NE; ++e) {
    k_transpose<<<dim3(DM / 32, HD / 32), 256, 0, stream>>>(
        keys + (size_t)e * HD, keysT + (size_t)e * HD * DM, DM, HD, NE * HD);
    k_transpose<<<dim3(HD / 32, DM / 32), 256, 0, stream>>>(
        vals + (size_t)e * DM, valsT + (size_t)e * DM * HD, HD, DM, NE * DM);
  }

  // shared expert: sh = gelu(xb @ skT + skeyb); out = sh @ svT + svalb
  k_gemm8p<0><<<(TOK/256)*(HD/256), 512, 0, stream>>>(
      xb, 0, DM, skT, 0, DM, sh, 0, HD, skeyb, 0, DM, TOK/256, HD/256);
  k_gemm8p<2><<<(TOK/256)*(DM/256), 512, 0, stream>>>(
      sh, 0, HD, svT, 0, HD, out, 0, DM, svalb, 0, HD, TOK/256, DM/256);

  // MoE experts
  k_gemm8p<0><<<(MEP/256)*(HD/256)*NE, 512, 0, stream>>>(
      exp_in, (size_t)MEP * DM, DM, keysT, (size_t)HD * DM, DM,
      h, (size_t)MEP * HD, HD, keyb, HD, DM, MEP/256, HD/256);
  k_gemm8p<1><<<(MEP/256)*(DM/256)*NE, 512, 0, stream>>>(
      h, (size_t)MEP * HD, HD, valsT, (size_t)DM * HD, HD,
      eo, (size_t)MEP * DM, DM, valb, DM, HD, MEP/256, DM/256);

  // combine: out += gate * eo[slot]
  k_combine<<<TOK, 256, 0, stream>>>(tok_slot, gsel, eo, out);
}

// Round 13
// 1221.329 us; speedup vs baseline: 1.5635x; 1.0020x over previous
//
#include <hip/hip_runtime.h>
#include <hip/hip_bf16.h>

typedef unsigned short u16;
typedef __attribute__((ext_vector_type(8))) __bf16 bf16x8;
typedef __attribute__((ext_vector_type(4))) float f32x4;

#define TOK 16384
#define DM  1024
#define HD  4096
#define NE  8
#define NG  128
#define GSZ 128
#define CAPM 31               // usable slots per (group, expert)
#define MEP (NG*32)           // 4096 padded rows per expert (slot 31 = zero pad)

static __device__ __forceinline__ u16 f2b(float f) {
  union { float f; unsigned u; } v; v.f = f;
  unsigned r = v.u + 0x7fffu + ((v.u >> 16) & 1u);
  return (u16)(r >> 16);
}
static __device__ __forceinline__ float b2f(u16 u) {
  union { unsigned u; float f; } v; v.u = (unsigned)u << 16; return v.f;
}

// jax.nn.gelu default = tanh approximation
static __device__ __forceinline__ float gelu_f(float x) {
  float y = 0.7978845608028654f * (x + 0.044715f * x * x * x);
  float t = __expf(-2.0f * fabsf(y));
  float th = (1.0f - t) / (1.0f + t);
  th = (y < 0.0f) ? -th : th;
  return 0.5f * x * (1.0f + th);
}

static __device__ __forceinline__ void gl2lds16(const void* g, void* l) {
  __builtin_amdgcn_global_load_lds(
      (const __attribute__((address_space(1))) void*)g,
      (__attribute__((address_space(3))) void*)l, 16, 0, 0);
}

// ------ router: logits (fp64 accum), softmax, top-2; also emits xb bf16 -----
__global__ __launch_bounds__(256) void k_router(
    const float* __restrict__ x, const float* __restrict__ gw,
    const float* __restrict__ gb, int* __restrict__ e_sel,
    float* __restrict__ gsel, u16* __restrict__ xb) {
  int wave = threadIdx.x >> 6, lane = threadIdx.x & 63;
  int t = blockIdx.x * 4 + wave;
  const float* xr = x + (size_t)t * DM;
  double acc[8] = {0,0,0,0,0,0,0,0};
  for (int d0 = lane * 4; d0 < DM; d0 += 256) {
    float4 xv = *(const float4*)(xr + d0);
    ushort4 xo; xo.x=f2b(xv.x); xo.y=f2b(xv.y); xo.z=f2b(xv.z); xo.w=f2b(xv.w);
    *(ushort4*)(xb + (size_t)t * DM + d0) = xo;        // fused cast
    float xa[4] = {xv.x, xv.y, xv.z, xv.w};
    const float* g0 = gw + (size_t)d0 * NE;
#pragma unroll
    for (int dd = 0; dd < 4; ++dd)
#pragma unroll
      for (int e = 0; e < 8; ++e)
        acc[e] += (double)xa[dd] * (double)g0[dd * 8 + e];
  }
#pragma unroll
  for (int off = 32; off > 0; off >>= 1)
#pragma unroll
    for (int e = 0; e < 8; ++e)
      acc[e] += __shfl_down(acc[e], off, 64);
  if (lane == 0) {
    float l[8];
#pragma unroll
    for (int e = 0; e < 8; ++e) l[e] = (float)acc[e] + gb[e];
    int e0 = 0;
    for (int e = 1; e < 8; ++e) if (l[e] > l[e0]) e0 = e;
    int e1 = (e0 == 0) ? 1 : 0;
    for (int e = 0; e < 8; ++e) if (e != e0 && l[e] > l[e1]) e1 = e;
    float m = l[e0], s = 0.f, p[8];
    for (int e = 0; e < 8; ++e) { p[e] = expf(l[e] - m); s += p[e]; }
    e_sel[t] = e0; e_sel[TOK + t] = e1;
    gsel[t] = p[e0] / s; gsel[TOK + t] = p[e1] / s;
  }
}

// ------------- capacity assignment: serial cumsum per group, per-k ----------
__global__ void k_assign(const int* __restrict__ e_sel,
                         int* __restrict__ tok_slot, int* __restrict__ slot_tok) {
  int g = blockIdx.x;
  for (int i = threadIdx.x; i < NE * 32 * 2; i += 64) {
    int e = i >> 6, rem = i & 63, c = rem >> 1, k = rem & 1;
    slot_tok[((size_t)(e * MEP + g * 32 + c)) * 2 + k] = -1;
  }
  __syncthreads();
  if (threadIdx.x == 0) {
    int cnt[2][NE];
    for (int k = 0; k < 2; ++k) for (int e = 0; e < NE; ++e) cnt[k][e] = 0;
    for (int s = 0; s < GSZ; ++s) {
      int t = g * GSZ + s;
      for (int k = 0; k < 2; ++k) {
        int e = e_sel[k * TOK + t];
        int r = ++cnt[k][e];
        if (r <= CAPM) {
          int m = e * MEP + g * 32 + (r - 1);
          tok_slot[k * TOK + t] = m;
          slot_tok[(size_t)m * 2 + k] = t;
        } else tok_slot[k * TOK + t] = -1;
      }
    }
  }
}

// -- exp_in[m,:] = bf16( xb[t0] + xb[t1] ) (bf16 gather); pad slots -> 0 -----
__global__ __launch_bounds__(128) void k_build_expin(
    const u16* __restrict__ xb, const int* __restrict__ slot_tok,
    u16* __restrict__ exp_in) {
  int m = blockIdx.x;
  int t0 = slot_tok[(size_t)m * 2], t1 = slot_tok[(size_t)m * 2 + 1];
  int d = threadIdx.x * 8;
  float v[8] = {0,0,0,0,0,0,0,0};
  if (t0 >= 0) {
    const ushort4* p = (const ushort4*)(xb + (size_t)t0 * DM + d);
    ushort4 a = p[0], b = p[1];
    v[0]+=b2f(a.x); v[1]+=b2f(a.y); v[2]+=b2f(a.z); v[3]+=b2f(a.w);
    v[4]+=b2f(b.x); v[5]+=b2f(b.y); v[6]+=b2f(b.z); v[7]+=b2f(b.w);
  }
  if (t1 >= 0) {
    const ushort4* p = (const ushort4*)(xb + (size_t)t1 * DM + d);
    ushort4 a = p[0], b = p[1];
    v[0]+=b2f(a.x); v[1]+=b2f(a.y); v[2]+=b2f(a.z); v[3]+=b2f(a.w);
    v[4]+=b2f(b.x); v[5]+=b2f(b.y); v[6]+=b2f(b.z); v[7]+=b2f(b.w);
  }
  ushort4 o0, o1;
  o0.x=f2b(v[0]); o0.y=f2b(v[1]); o0.z=f2b(v[2]); o0.w=f2b(v[3]);
  o1.x=f2b(v[4]); o1.y=f2b(v[5]); o1.z=f2b(v[6]); o1.w=f2b(v[7]);
  *(ushort4*)(exp_in + (size_t)m * DM + d) = o0;
  *(ushort4*)(exp_in + (size_t)m * DM + d + 4) = o1;
}

// -- transpose+cast (z-grid): in(k,n) fp32 [z*izo + k*rs + n] -> bf16 out ----
__global__ __launch_bounds__(256) void k_transpose(
    const float* __restrict__ in, u16* __restrict__ out,
    int K, int N, int rs, size_t izo, size_t ozo) {
  __shared__ float tile[32][33];
  in += (size_t)blockIdx.z * izo;
  out += (size_t)blockIdx.z * ozo;
  int k0 = blockIdx.x * 32, n0 = blockIdx.y * 32;
  int tx = threadIdx.x & 31, ty = threadIdx.x >> 5;
#pragma unroll
  for (int i = 0; i < 4; ++i)
    tile[ty + i * 8][tx] = in[(size_t)(k0 + ty + i * 8) * rs + n0 + tx];
  __syncthreads();
#pragma unroll
  for (int i = 0; i < 4; ++i) {
    int n = ty + i * 8;
    out[(size_t)(n0 + n) * K + k0 + tx] = f2b(tile[tx][n]);
  }
}

// ---- 256x256 bf16 MFMA GEMM, 8-phase counted-vmcnt, ONE barrier/phase ------
// Round-12 verified schedule. EPI 0: bf16 gelu(acc+bias); 1: bf16 acc+bias;
// 2: f32 acc+bias; 3: f32 acc+bias + fused MoE combine (reads eo/slots/gates;
// same adds in the same order as the old separate k_combine -> bit-identical).

#define PH_MID() \
  __builtin_amdgcn_s_setprio(1);

#define PH_END() \
  __builtin_amdgcn_s_setprio(0); \
  asm volatile("s_waitcnt vmcnt(4)" ::: "memory"); \
  __builtin_amdgcn_s_barrier();

#define PH_END0() \
  __builtin_amdgcn_s_setprio(0); \
  asm volatile("s_waitcnt vmcnt(0)" ::: "memory"); \
  __builtin_amdgcn_s_barrier();

#define PH_ENDN() \
  __builtin_amdgcn_s_setprio(0); \
  __builtin_amdgcn_s_barrier();

#define STG(gp, ld, lds) \
  gl2lds16((gp) + (size_t)srow * (ld) + scol, (lds) + sdst); \
  gl2lds16((gp) + (size_t)(srow + 64) * (ld) + scol, (lds) + 4096 + sdst);

#define RD_A(SLOT) \
  _Pragma("unroll") for (int k2 = 0; k2 < 2; ++k2) \
    _Pragma("unroll") for (int mi = 0; mi < 4; ++mi) \
      a[k2][mi] = *(const bf16x8*)(&HA[SLOT][0] + offA[k2][mi]);

#define RD_BA(SLOT) \
  _Pragma("unroll") for (int k2 = 0; k2 < 2; ++k2) \
    _Pragma("unroll") for (int ni = 0; ni < 2; ++ni) \
      bA[k2][ni] = *(const bf16x8*)(&HB[SLOT][0] + offB[k2][ni]);

#define RD_BB(SLOT) \
  _Pragma("unroll") for (int k2 = 0; k2 < 2; ++k2) \
    _Pragma("unroll") for (int ni = 0; ni < 2; ++ni) \
      bB[k2][ni] = *(const bf16x8*)(&HB[SLOT][0] + offB[k2][ni]);

#define MM(BM, MOFF, NOFF) \
  _Pragma("unroll") for (int k2 = 0; k2 < 2; ++k2) \
    _Pragma("unroll") for (int mi = 0; mi < 4; ++mi) \
      _Pragma("unroll") for (int ni = 0; ni < 2; ++ni) \
        acc[mi + MOFF][ni + NOFF] = __builtin_amdgcn_mfma_f32_16x16x32_bf16( \
            a[k2][mi], BM[k2][ni], acc[mi + MOFF][ni + NOFF], 0, 0, 0);

#define TILE(T, SA0, SA1, SB0, SB1, DA0, DA1, DB0, DB1) { \
  const u16* An = Ab + ((T) + 1) * 64; \
  const u16* Bn = Bb + ((T) + 1) * 64; \
  RD_A(SA0); RD_BA(SB0); \
  STG(An, lda, &HA[DA0][0]); \
  PH_MID(); MM(bA, 0, 0); PH_END(); \
  RD_BB(SB1); \
  STG(Bn, ldb, &HB[DB0][0]); \
  PH_MID(); MM(bB, 0, 2); PH_END(); \
  RD_A(SA1); \
  STG(Bn + (size_t)128 * ldb, ldb, &HB[DB1][0]); \
  PH_MID(); MM(bB, 4, 2); PH_END(); \
  STG(An + (size_t)128 * lda, lda, &HA[DA1][0]); \
  PH_MID(); MM(bA, 4, 0); PH_END(); \
}

#define TILE_LAST(SA0, SA1, SB0, SB1) { \
  RD_A(SA0); RD_BA(SB0); \
  PH_MID(); MM(bA, 0, 0); PH_END0(); \
  RD_BB(SB1); \
  PH_MID(); MM(bB, 0, 2); PH_ENDN(); \
  RD_A(SA1); \
  PH_MID(); MM(bB, 4, 2); PH_ENDN(); \
  PH_MID(); MM(bA, 4, 0); PH_ENDN(); \
}

template <int EPI>
__global__ __launch_bounds__(512, 2) void k_gemm8p(
    const u16* __restrict__ A, size_t sAe, int lda,
    const u16* __restrict__ B, size_t sBe, int ldb,
    void* __restrict__ Cv, size_t sCe, int ldc,
    const float* __restrict__ bias, int sBiasE, int K, int gx, int gy,
    const u16* __restrict__ eo, const int* __restrict__ tsl,
    const float* __restrict__ gs) {
  __shared__ __align__(16) u16 HA[4][128 * 64];
  __shared__ __align__(16) u16 HB[4][128 * 64];
  const int tid = threadIdx.x;
  const int lane = tid & 63, wid = tid >> 6;
  const int wr = wid >> 2, wc = wid & 3;
  const int la15 = lane & 15, hi = lane >> 4;

  // T1: bijective XCD-chunked remap of 1D grid (gridDim.x % 8 == 0)
  int nwg = gridDim.x, per = nwg >> 3;
  int wg = (blockIdx.x & 7) * per + (blockIdx.x >> 3);
  int bx = wg % gx, tmp = wg / gx;
  int by = tmp % gy, z = tmp / gy;

  const u16* Ab = A + (size_t)z * sAe + (size_t)(bx * 256) * lda;
  const u16* Bb = B + (size_t)z * sBe + (size_t)(by * 256) * ldb;

  // per-lane ds_read element offsets (identical for every ring slot)
  int offA[2][4], offB[2][2];
#pragma unroll
  for (int k2 = 0; k2 < 2; ++k2) {
    int sl = k2 * 4 + hi;
#pragma unroll
    for (int mi = 0; mi < 4; ++mi) {
      int r = (mi * 2 + wr) * 16 + la15;
      offA[k2][mi] = r * 64 + ((sl ^ (r & 7)) << 3);
    }
#pragma unroll
    for (int ni = 0; ni < 2; ++ni) {
      int r = (ni * 4 + wc) * 16 + la15;
      offB[k2][ni] = r * 64 + ((sl ^ (r & 7)) << 3);
    }
  }
  // per-lane stage offsets (inverse-swizzled global src, linear LDS dest)
  const int srow = tid >> 3;
  const int scol = (((tid & 7) ^ (srow & 7)) << 3);
  const int sdst = (tid & ~63) * 8;

  f32x4 acc[8][4] = {};
  const int NT = K >> 6;

  bf16x8 a[2][4], bA[2][2], bB[2][2];

  // prologue: tile 0 (4 halves), full drain once
  STG(Ab, lda, &HA[0][0]);
  STG(Bb, ldb, &HB[0][0]);
  STG(Bb + (size_t)128 * ldb, ldb, &HB[1][0]);
  STG(Ab + (size_t)128 * lda, lda, &HA[1][0]);
  asm volatile("s_waitcnt vmcnt(0)" ::: "memory");
  __builtin_amdgcn_s_barrier();

  for (int t = 0; t + 2 < NT; t += 2) {
    TILE(t,     0, 1, 0, 1, 2, 3, 2, 3);
    TILE(t + 1, 2, 3, 2, 3, 0, 1, 0, 1);
  }
  TILE(NT - 2, 0, 1, 0, 1, 2, 3, 2, 3);
  TILE_LAST(2, 3, 2, 3);

  // epilogue (strided mapping)
  const int hi4 = hi << 2;
  if (EPI == 3) {
    float bv[4];
#pragma unroll
    for (int ni = 0; ni < 4; ++ni)
      bv[ni] = bias[by * 256 + (ni * 4 + wc) * 16 + la15];
#pragma unroll
    for (int mi = 0; mi < 8; ++mi) {
#pragma unroll
      for (int j = 0; j < 4; ++j) {
        int t = bx * 256 + (mi * 2 + wr) * 16 + hi4 + j;
        int m0 = tsl[t], m1 = tsl[TOK + t];
        float g0 = gs[t], g1 = gs[TOK + t];
#pragma unroll
        for (int ni = 0; ni < 4; ++ni) {
          int col = by * 256 + (ni * 4 + wc) * 16 + la15;
          float val = acc[mi][ni][j] + bv[ni];
          if (m0 >= 0) val += g0 * b2f(eo[(size_t)m0 * DM + col]);
          if (m1 >= 0) val += g1 * b2f(eo[(size_t)m1 * DM + col]);
          ((float*)Cv)[(size_t)t * ldc + col] = val;
        }
      }
    }
  } else {
#pragma unroll
    for (int ni = 0; ni < 4; ++ni) {
      int col = by * 256 + (ni * 4 + wc) * 16 + la15;
      float bvv = bias[(size_t)z * sBiasE + col];
#pragma unroll
      for (int mi = 0; mi < 8; ++mi) {
        int row0 = bx * 256 + (mi * 2 + wr) * 16 + hi4;
        f32x4 v = acc[mi][ni];
#pragma unroll
        for (int j = 0; j < 4; ++j) {
          int row = row0 + j;
          float val = v[j] + bvv;
          if (EPI == 0)
            ((u16*)Cv)[(size_t)z * sCe + (size_t)row * ldc + col] = f2b(gelu_f(val));
          else if (EPI == 1)
            ((u16*)Cv)[(size_t)z * sCe + (size_t)row * ldc + col] = f2b(val);
          else
            ((float*)Cv)[(size_t)z * sCe + (size_t)row * ldc + col] = val;
        }
      }
    }
  }
}

__global__ void k_report(float* out, float code) { out[0] = code; }

extern "C" void kernel_launch(void* const* d_in, const int* in_sizes, int n_in,
                              void* d_out, int out_size, void* d_ws, size_t ws_size,
                              hipStream_t stream) {
  (void)in_sizes; (void)n_in;
  const float* x     = (const float*)d_in[0];
  const float* gw    = (const float*)d_in[1];
  const float* gb    = (const float*)d_in[2];
  const float* keys  = (const float*)d_in[3];
  const float* keyb  = (const float*)d_in[4];
  const float* vals  = (const float*)d_in[5];
  const float* valb  = (const float*)d_in[6];
  const float* skey  = (const float*)d_in[7];
  const float* skeyb = (const float*)d_in[8];
  const float* sval  = (const float*)d_in[9];
  const float* svalb = (const float*)d_in[10];
  float* out = (float*)d_out;

  char* ws = (char*)d_ws;
  size_t off = 0;
  auto alloc = [&](size_t bytes) -> char* {
    char* p = ws + off; off += (bytes + 255) & ~(size_t)255; return p;
  };
  int*   e_sel    = (int*)  alloc(2 * TOK * 4);
  float* gsel     = (float*)alloc(2 * TOK * 4);
  int*   tok_slot = (int*)  alloc(2 * TOK * 4);
  int*   slot_tok = (int*)  alloc((size_t)NE * MEP * 2 * 4);

  u16* xb     = (u16*)alloc((size_t)TOK * DM * 2);         // 32MB, live whole call
  u16* skT    = (u16*)alloc((size_t)HD * DM * 2);          // 8MB
  u16* svT    = (u16*)alloc((size_t)DM * HD * 2);          // 8MB
  u16* exp_in = (u16*)alloc((size_t)NE * MEP * DM * 2);    // 64MB
  u16* eo     = exp_in;            // alias: exp_in dead after MoE G1
  u16* keysT  = (u16*)alloc((size_t)NE * HD * DM * 2);     // 64MB
  u16* valsT  = (u16*)alloc((size_t)NE * DM * HD * 2);     // 64MB

  size_t sh_b = (size_t)TOK * HD * 2;          // union: h then sh
  size_t h_b  = (size_t)NE * MEP * HD * 2;
  u16* sh = (u16*)(ws + off);
  u16* h  = (u16*)(ws + off);
  size_t need = off + (sh_b > h_b ? sh_b : h_b);

  if (need > ws_size) {                        // sentinel: out[0] = -available MB
    hipMemsetAsync(d_out, 0, (size_t)out_size * 4, stream);
    k_report<<<1, 1, 0, stream>>>(out, -(float)(ws_size >> 20));
    return;
  }

  // routing (+fused x->bf16 cast) + assignment + dispatch gather (bf16)
  k_router<<<TOK / 4, 256, 0, stream>>>(x, gw, gb, e_sel, gsel, xb);
  k_assign<<<NG, 64, 0, stream>>>(e_sel, tok_slot, slot_tok);
  k_build_expin<<<NE * MEP, 128, 0, stream>>>(xb, slot_tok, exp_in);

  // weight transposes (z-grid for per-expert)
  k_transpose<<<dim3(DM / 32, HD / 32, 1), 256, 0, stream>>>(
      skey, skT, DM, HD, HD, 0, 0);
  k_transpose<<<dim3(HD / 32, DM / 32, 1), 256, 0, stream>>>(
      sval, svT, HD, DM, DM, 0, 0);
  k_transpose<<<dim3(DM / 32, HD / 32, NE), 256, 0, stream>>>(
      keys, keysT, DM, HD, NE * HD, (size_t)HD, (size_t)HD * DM);
  k_transpose<<<dim3(HD / 32, DM / 32, NE), 256, 0, stream>>>(
      vals, valsT, HD, DM, NE * DM, (size_t)DM, (size_t)DM * HD);

  // MoE experts first (h -> sh region reuse; eo aliases exp_in)
  k_gemm8p<0><<<(MEP/256)*(HD/256)*NE, 512, 0, stream>>>(
      exp_in, (size_t)MEP * DM, DM, keysT, (size_t)HD * DM, DM,
      h, (size_t)MEP * HD, HD, keyb, HD, DM, MEP/256, HD/256,
      nullptr, nullptr, nullptr);
  k_gemm8p<1><<<(MEP/256)*(DM/256)*NE, 512, 0, stream>>>(
      h, (size_t)MEP * HD, HD, valsT, (size_t)DM * HD, HD,
      eo, (size_t)MEP * DM, DM, valb, DM, HD, MEP/256, DM/256,
      nullptr, nullptr, nullptr);

  // shared expert: sh = gelu(xb @ skT + skeyb) (overwrites h - dead);
  // out = sh @ svT + svalb + fused combine(gate x eo[slot])
  k_gemm8p<0><<<(TOK/256)*(HD/256), 512, 0, stream>>>(
      xb, 0, DM, skT, 0, DM, sh, 0, HD, skeyb, 0, DM, TOK/256, HD/256,
      nullptr, nullptr, nullptr);
  k_gemm8p<3><<<(TOK/256)*(DM/256), 512, 0, stream>>>(
      sh, 0, HD, svT, 0, HD, out, 0, DM, svalb, 0, HD, TOK/256, DM/256,
      eo, tok_slot, gsel);
}